// Round 1
// baseline (4599.470 us; speedup 1.0000x reference)
//
#include <hip/hip_runtime.h>
#include <hip/hip_bf16.h>

#define N_NODES 50000
#define N_EDGES 800000
#define D 128

// ---------------- degree ----------------
__global__ __launch_bounds__(256) void deg_kernel(const int* __restrict__ dst,
                                                  float* __restrict__ deg, int n) {
  int e = blockIdx.x * 256 + threadIdx.x;
  if (e < n) atomicAdd(&deg[dst[e]], 1.0f);
}

__global__ __launch_bounds__(256) void inv_deg_kernel(float* __restrict__ deg, int n) {
  int i = blockIdx.x * 256 + threadIdx.x;
  if (i < n) deg[i] = 1.0f / fmaxf(deg[i], 1.0f);
}

// ---------------- scatter-add aggregation ----------------
// 32 threads per edge, 4 floats per thread (float4 load, 4 f32 atomics).
__global__ __launch_bounds__(256) void scatter_add(const float* __restrict__ h,
                                                   const int* __restrict__ src,
                                                   const int* __restrict__ dst,
                                                   float* __restrict__ agg) {
  int idx = blockIdx.x * 256 + threadIdx.x;
  int e = idx >> 5;
  int q = (idx & 31) << 2;
  int s = src[e];
  int d = dst[e];
  float4 v = *(const float4*)(h + (size_t)s * D + q);
  float* ap = agg + (size_t)d * D + q;
  atomicAdd(ap + 0, v.x);
  atomicAdd(ap + 1, v.y);
  atomicAdd(ap + 2, v.z);
  atomicAdd(ap + 3, v.w);
}

// ---------------- fused dual-GEMM + bias + activation ----------------
__device__ __forceinline__ float selu_f(float x) {
  const float alpha = 1.6732632423543772f;
  const float scale = 1.0507009873554805f;
  return scale * (x > 0.0f ? x : alpha * expm1f(x));
}

// out[n,:] = act( h[n,:] @ Ws + (agg[n,:]*inv_deg[n]) @ Wn + b )
// Block: 256 threads. Each thread computes 4 output columns of one row.
template <int DOUT, int ACT>
__global__ __launch_bounds__(256) void gemm_fused(const float* __restrict__ h,
                                                  const float* __restrict__ agg,
                                                  const float* __restrict__ inv_deg,
                                                  const float* __restrict__ Ws,
                                                  const float* __restrict__ Wn,
                                                  const float* __restrict__ bias,
                                                  float* __restrict__ out) {
  constexpr int CG = DOUT / 4;   // column groups (float4 each)
  constexpr int R = 256 / CG;    // rows per block (8 for DOUT=128, 16 for DOUT=64)
  __shared__ float hs[R][D + 4]; // +4 pad: distinct banks across rows in a wave
  __shared__ float ms[R][D + 4];

  const int tid = threadIdx.x;
  const int row0 = blockIdx.x * R;

  constexpr int L4 = (R * (D / 4)) / 256;  // float4 loads per thread per matrix
#pragma unroll
  for (int i = 0; i < L4; ++i) {
    int idx = tid + i * 256;
    int r = idx >> 5;
    int c4 = (idx & 31) << 2;
    int node = row0 + r;
    *(float4*)&hs[r][c4] = *(const float4*)(h + (size_t)node * D + c4);
    float sc = inv_deg[node];
    float4 av = *(const float4*)(agg + (size_t)node * D + c4);
    av.x *= sc; av.y *= sc; av.z *= sc; av.w *= sc;
    *(float4*)&ms[r][c4] = av;
  }
  __syncthreads();

  const int cg = tid % CG;
  const int r = tid / CG;
  const int c0 = cg << 2;

  float4 acc = *(const float4*)(bias + c0);
#pragma unroll 4
  for (int k = 0; k < D; ++k) {
    float hk = hs[r][k];
    float mk = ms[r][k];
    float4 w1 = *(const float4*)(Ws + k * DOUT + c0);
    float4 w2 = *(const float4*)(Wn + k * DOUT + c0);
    acc.x += hk * w1.x + mk * w2.x;
    acc.y += hk * w1.y + mk * w2.y;
    acc.z += hk * w1.z + mk * w2.z;
    acc.w += hk * w1.w + mk * w2.w;
  }
  if (ACT == 1) {
    acc.x = selu_f(acc.x);
    acc.y = selu_f(acc.y);
    acc.z = selu_f(acc.z);
    acc.w = selu_f(acc.w);
  }
  *(float4*)(out + (size_t)(row0 + r) * DOUT + c0) = acc;
}

// ---------------- row softmax over 64 classes (1 row per 64-lane wave) ----------------
__global__ __launch_bounds__(256) void softmax64(float* __restrict__ out) {
  int idx = blockIdx.x * 256 + threadIdx.x;
  float v = out[idx];
  float m = v;
#pragma unroll
  for (int o = 32; o > 0; o >>= 1) m = fmaxf(m, __shfl_xor(m, o, 64));
  float e = expf(v - m);
  float s = e;
#pragma unroll
  for (int o = 32; o > 0; o >>= 1) s += __shfl_xor(s, o, 64);
  out[idx] = e / s;
}

extern "C" void kernel_launch(void* const* d_in, const int* in_sizes, int n_in,
                              void* d_out, int out_size, void* d_ws, size_t ws_size,
                              hipStream_t stream) {
  const float* x   = (const float*)d_in[0];
  const int* src   = (const int*)d_in[1];
  const int* dst   = (const int*)d_in[2];
  const float* Ws0 = (const float*)d_in[3];
  const float* Wn0 = (const float*)d_in[4];
  const float* b0  = (const float*)d_in[5];
  const float* Ws1 = (const float*)d_in[6];
  const float* Wn1 = (const float*)d_in[7];
  const float* b1  = (const float*)d_in[8];
  const float* Ws2 = (const float*)d_in[9];
  const float* Wn2 = (const float*)d_in[10];
  const float* b2  = (const float*)d_in[11];
  float* out = (float*)d_out;

  // workspace layout (floats): deg[N] | h1[N*D] | h2[N*D] | agg[N*D]  (~77 MB)
  float* ws  = (float*)d_ws;
  float* deg = ws;
  float* h1  = ws + 50048;  // 16B-aligned pad past N_NODES
  float* h2  = h1 + (size_t)N_NODES * D;
  float* agg = h2 + (size_t)N_NODES * D;

  const size_t aggBytes = (size_t)N_NODES * D * sizeof(float);

  hipMemsetAsync(deg, 0, N_NODES * sizeof(float), stream);
  deg_kernel<<<(N_EDGES + 255) / 256, 256, 0, stream>>>(dst, deg, N_EDGES);
  inv_deg_kernel<<<(N_NODES + 255) / 256, 256, 0, stream>>>(deg, N_NODES);

  // layer 0: x -> h1 (selu)
  hipMemsetAsync(agg, 0, aggBytes, stream);
  scatter_add<<<(N_EDGES * 32) / 256, 256, 0, stream>>>(x, src, dst, agg);
  gemm_fused<128, 1><<<N_NODES / 8, 256, 0, stream>>>(x, agg, deg, Ws0, Wn0, b0, h1);

  // layer 1: h1 -> h2 (selu)
  hipMemsetAsync(agg, 0, aggBytes, stream);
  scatter_add<<<(N_EDGES * 32) / 256, 256, 0, stream>>>(h1, src, dst, agg);
  gemm_fused<128, 1><<<N_NODES / 8, 256, 0, stream>>>(h1, agg, deg, Ws1, Wn1, b1, h2);

  // layer 2: h2 -> out (logits), then softmax
  hipMemsetAsync(agg, 0, aggBytes, stream);
  scatter_add<<<(N_EDGES * 32) / 256, 256, 0, stream>>>(h2, src, dst, agg);
  gemm_fused<64, 0><<<N_NODES / 16, 256, 0, stream>>>(h2, agg, deg, Ws2, Wn2, b2, out);
  softmax64<<<(N_NODES * 64) / 256, 256, 0, stream>>>(out);
}

// Round 2
// 841.742 us; speedup vs baseline: 5.4642x; 5.4642x over previous
//
#include <hip/hip_runtime.h>
#include <hip/hip_bf16.h>

#define N_NODES 50000
#define N_EDGES 800000
#define D 128

// ================= CSR build =================
__global__ __launch_bounds__(256) void hist_kernel(const int* __restrict__ dst,
                                                   int* __restrict__ cnt) {
  int e = blockIdx.x * 256 + threadIdx.x;
  if (e < N_EDGES) atomicAdd(&cnt[dst[e]], 1);
}

// single-workgroup exclusive scan of cnt[0..N_NODES) -> cursor (start offsets)
__global__ __launch_bounds__(1024) void scan_kernel(const int* __restrict__ cnt,
                                                    int* __restrict__ cursor) {
  __shared__ int sums[1024];
  const int tid = threadIdx.x;
  const int CH = (N_NODES + 1023) / 1024;  // 49
  const int base = tid * CH;
  int s = 0;
  for (int i = 0; i < CH; ++i) {
    int idx = base + i;
    if (idx < N_NODES) s += cnt[idx];
  }
  sums[tid] = s;
  __syncthreads();
  for (int off = 1; off < 1024; off <<= 1) {
    int v = (tid >= off) ? sums[tid - off] : 0;
    __syncthreads();
    sums[tid] += v;
    __syncthreads();
  }
  int excl = (tid == 0) ? 0 : sums[tid - 1];
  for (int i = 0; i < CH; ++i) {
    int idx = base + i;
    if (idx < N_NODES) {
      int c = cnt[idx];
      cursor[idx] = excl;
      excl += c;
    }
  }
}

// fill: cursor[n] goes from start offset -> end offset as edges append
__global__ __launch_bounds__(256) void fill_kernel(const int* __restrict__ src,
                                                   const int* __restrict__ dst,
                                                   int* __restrict__ cursor,
                                                   int* __restrict__ csr_src) {
  int e = blockIdx.x * 256 + threadIdx.x;
  if (e < N_EDGES) {
    int pos = atomicAdd(&cursor[dst[e]], 1);
    csr_src[pos] = src[e];
  }
}

// ================= gather-mean =================
// 64 lanes per node (float2/lane); after fill_kernel cursor[n] = end(n),
// start(n) = cursor[n-1] (or 0).
__global__ __launch_bounds__(256) void gather_mean(const float* __restrict__ h,
                                                   const int* __restrict__ cursor,
                                                   const int* __restrict__ csr_src,
                                                   float* __restrict__ mean) {
  const int n = blockIdx.x * 4 + (threadIdx.x >> 6);
  const int lane = threadIdx.x & 63;
  const int end = cursor[n];
  const int start = (n == 0) ? 0 : cursor[n - 1];
  const float* hp = h + lane * 2;
  float2 acc = make_float2(0.0f, 0.0f);
  int e = start;
  for (; e + 1 < end; e += 2) {
    int s0 = csr_src[e];
    int s1 = csr_src[e + 1];
    float2 v0 = *(const float2*)(hp + (size_t)s0 * D);
    float2 v1 = *(const float2*)(hp + (size_t)s1 * D);
    acc.x += v0.x + v1.x;
    acc.y += v0.y + v1.y;
  }
  if (e < end) {
    int s0 = csr_src[e];
    float2 v0 = *(const float2*)(hp + (size_t)s0 * D);
    acc.x += v0.x;
    acc.y += v0.y;
  }
  float inv = 1.0f / (float)max(end - start, 1);
  acc.x *= inv;
  acc.y *= inv;
  *(float2*)(mean + (size_t)n * D + lane * 2) = acc;
}

// ================= fused dual-GEMM + bias + activation =================
__device__ __forceinline__ float selu_f(float x) {
  const float alpha = 1.6732632423543772f;
  const float scale = 1.0507009873554805f;
  return scale * (x > 0.0f ? x : alpha * expm1f(x));
}

// out[n,:] = act( h[n,:] @ Ws + mean[n,:] @ Wn + b )
template <int DOUT, int ACT>
__global__ __launch_bounds__(256) void gemm_fused(const float* __restrict__ h,
                                                  const float* __restrict__ mean,
                                                  const float* __restrict__ Ws,
                                                  const float* __restrict__ Wn,
                                                  const float* __restrict__ bias,
                                                  float* __restrict__ out) {
  constexpr int CG = DOUT / 4;   // column groups (float4 each)
  constexpr int R = 256 / CG;    // rows per block
  __shared__ float hs[R][D + 4];
  __shared__ float ms[R][D + 4];

  const int tid = threadIdx.x;
  const int row0 = blockIdx.x * R;

  constexpr int L4 = (R * (D / 4)) / 256;
#pragma unroll
  for (int i = 0; i < L4; ++i) {
    int idx = tid + i * 256;
    int r = idx >> 5;
    int c4 = (idx & 31) << 2;
    int node = row0 + r;
    *(float4*)&hs[r][c4] = *(const float4*)(h + (size_t)node * D + c4);
    *(float4*)&ms[r][c4] = *(const float4*)(mean + (size_t)node * D + c4);
  }
  __syncthreads();

  const int cg = tid % CG;
  const int r = tid / CG;
  const int c0 = cg << 2;

  float4 acc = *(const float4*)(bias + c0);
#pragma unroll 4
  for (int k = 0; k < D; ++k) {
    float hk = hs[r][k];
    float mk = ms[r][k];
    float4 w1 = *(const float4*)(Ws + k * DOUT + c0);
    float4 w2 = *(const float4*)(Wn + k * DOUT + c0);
    acc.x += hk * w1.x + mk * w2.x;
    acc.y += hk * w1.y + mk * w2.y;
    acc.z += hk * w1.z + mk * w2.z;
    acc.w += hk * w1.w + mk * w2.w;
  }
  if (ACT == 1) {
    acc.x = selu_f(acc.x);
    acc.y = selu_f(acc.y);
    acc.z = selu_f(acc.z);
    acc.w = selu_f(acc.w);
  }
  *(float4*)(out + (size_t)(row0 + r) * DOUT + c0) = acc;
}

// ================= row softmax over 64 classes =================
__global__ __launch_bounds__(256) void softmax64(float* __restrict__ out) {
  int idx = blockIdx.x * 256 + threadIdx.x;
  float v = out[idx];
  float m = v;
#pragma unroll
  for (int o = 32; o > 0; o >>= 1) m = fmaxf(m, __shfl_xor(m, o, 64));
  float e = expf(v - m);
  float s = e;
#pragma unroll
  for (int o = 32; o > 0; o >>= 1) s += __shfl_xor(s, o, 64);
  out[idx] = e / s;
}

extern "C" void kernel_launch(void* const* d_in, const int* in_sizes, int n_in,
                              void* d_out, int out_size, void* d_ws, size_t ws_size,
                              hipStream_t stream) {
  const float* x   = (const float*)d_in[0];
  const int* src   = (const int*)d_in[1];
  const int* dst   = (const int*)d_in[2];
  const float* Ws0 = (const float*)d_in[3];
  const float* Wn0 = (const float*)d_in[4];
  const float* b0  = (const float*)d_in[5];
  const float* Ws1 = (const float*)d_in[6];
  const float* Wn1 = (const float*)d_in[7];
  const float* b1  = (const float*)d_in[8];
  const float* Ws2 = (const float*)d_in[9];
  const float* Wn2 = (const float*)d_in[10];
  const float* b2  = (const float*)d_in[11];
  float* out = (float*)d_out;

  // ws layout: cursor int[50048] | csr_src int[800000] | h1 f[6.4M] | h2 f[6.4M] | mean f[6.4M]
  int* cursor  = (int*)d_ws;
  int* csr_src = cursor + 50048;
  float* h1    = (float*)d_ws + 850048;
  float* h2    = h1 + (size_t)N_NODES * D;
  float* mean  = h2 + (size_t)N_NODES * D;

  // CSR build (cnt aliases the not-yet-used mean buffer)
  int* cnt = (int*)mean;
  hipMemsetAsync(cnt, 0, N_NODES * sizeof(int), stream);
  hist_kernel<<<(N_EDGES + 255) / 256, 256, 0, stream>>>(dst, cnt);
  scan_kernel<<<1, 1024, 0, stream>>>(cnt, cursor);
  fill_kernel<<<(N_EDGES + 255) / 256, 256, 0, stream>>>(src, dst, cursor, csr_src);

  // layer 0: x -> h1 (selu)
  gather_mean<<<N_NODES / 4, 256, 0, stream>>>(x, cursor, csr_src, mean);
  gemm_fused<128, 1><<<N_NODES / 8, 256, 0, stream>>>(x, mean, Ws0, Wn0, b0, h1);

  // layer 1: h1 -> h2 (selu)
  gather_mean<<<N_NODES / 4, 256, 0, stream>>>(h1, cursor, csr_src, mean);
  gemm_fused<128, 1><<<N_NODES / 8, 256, 0, stream>>>(h1, mean, Ws1, Wn1, b1, h2);

  // layer 2: h2 -> out (logits) then softmax
  gather_mean<<<N_NODES / 4, 256, 0, stream>>>(h2, cursor, csr_src, mean);
  gemm_fused<64, 0><<<N_NODES / 16, 256, 0, stream>>>(h2, mean, Ws2, Wn2, b2, out);
  softmax64<<<(N_NODES * 64) / 256, 256, 0, stream>>>(out);
}

// Round 3
// 553.892 us; speedup vs baseline: 8.3039x; 1.5197x over previous
//
#include <hip/hip_runtime.h>
#include <hip/hip_bf16.h>

#define N_NODES 50000
#define N_EDGES 800000
#define D 128

typedef __attribute__((ext_vector_type(8))) __bf16 bf16x8;
typedef __attribute__((ext_vector_type(4))) float f32x4;
typedef __attribute__((ext_vector_type(4))) unsigned short us4;

// ---- fp32 -> bf16 split helpers (RNE) ----
__device__ __forceinline__ unsigned short bf16_rne(float x) {
  unsigned u = __builtin_bit_cast(unsigned, x);
  unsigned r = u + 0x7fffu + ((u >> 16) & 1u);
  return (unsigned short)(r >> 16);
}
__device__ __forceinline__ float bf16_f(unsigned short b) {
  unsigned u = ((unsigned)b) << 16;
  return __builtin_bit_cast(float, u);
}
__device__ __forceinline__ void split2(float x, unsigned short& hi, unsigned short& lo) {
  hi = bf16_rne(x);
  lo = bf16_rne(x - bf16_f(hi));
}

__device__ __forceinline__ float selu_f(float x) {
  const float alpha = 1.6732632423543772f;
  const float scale = 1.0507009873554805f;
  return scale * (x > 0.0f ? x : alpha * expm1f(x));
}

// ================= CSR build =================
__global__ __launch_bounds__(256) void hist_kernel(const int* __restrict__ dst,
                                                   int* __restrict__ cnt) {
  int e = blockIdx.x * 256 + threadIdx.x;
  if (e < N_EDGES) atomicAdd(&cnt[dst[e]], 1);
}

__global__ __launch_bounds__(1024) void scan_kernel(const int* __restrict__ cnt,
                                                    int* __restrict__ cursor) {
  __shared__ int sums[1024];
  const int tid = threadIdx.x;
  const int CH = (N_NODES + 1023) / 1024;
  const int base = tid * CH;
  int s = 0;
  for (int i = 0; i < CH; ++i) {
    int idx = base + i;
    if (idx < N_NODES) s += cnt[idx];
  }
  sums[tid] = s;
  __syncthreads();
  for (int off = 1; off < 1024; off <<= 1) {
    int v = (tid >= off) ? sums[tid - off] : 0;
    __syncthreads();
    sums[tid] += v;
    __syncthreads();
  }
  int excl = (tid == 0) ? 0 : sums[tid - 1];
  for (int i = 0; i < CH; ++i) {
    int idx = base + i;
    if (idx < N_NODES) {
      int c = cnt[idx];
      cursor[idx] = excl;
      excl += c;
    }
  }
}

__global__ __launch_bounds__(256) void fill_kernel(const int* __restrict__ src,
                                                   const int* __restrict__ dst,
                                                   int* __restrict__ cursor,
                                                   int* __restrict__ csr_src) {
  int e = blockIdx.x * 256 + threadIdx.x;
  if (e < N_EDGES) {
    int pos = atomicAdd(&cursor[dst[e]], 1);
    csr_src[pos] = src[e];
  }
}

// ================= weight split/transpose precompute =================
// WT layouts (k-major): wt0/wt1: [n(128)][k(256)] with k<128 -> Ws, k>=128 -> Wn
//                       wt2:     [n(128)][k(128)] with n<64 -> Ws2 col n, n>=64 -> Wn2 col n-64
__global__ __launch_bounds__(256) void wsplit_kernel(
    const float* __restrict__ Ws0, const float* __restrict__ Wn0,
    const float* __restrict__ Ws1, const float* __restrict__ Wn1,
    const float* __restrict__ Ws2, const float* __restrict__ Wn2,
    const float* __restrict__ b2,
    unsigned short* __restrict__ wt0h, unsigned short* __restrict__ wt0l,
    unsigned short* __restrict__ wt1h, unsigned short* __restrict__ wt1l,
    unsigned short* __restrict__ wt2h, unsigned short* __restrict__ wt2l,
    float* __restrict__ b2ext) {
  int idx = blockIdx.x * 256 + threadIdx.x;
  if (idx < 32768) {
    int n = idx >> 8, k = idx & 255;
    float wv = (k < 128) ? Ws0[k * 128 + n] : Wn0[(k - 128) * 128 + n];
    unsigned short h, l; split2(wv, h, l);
    wt0h[idx] = h; wt0l[idx] = l;
  } else if (idx < 65536) {
    int j = idx - 32768;
    int n = j >> 8, k = j & 255;
    float wv = (k < 128) ? Ws1[k * 128 + n] : Wn1[(k - 128) * 128 + n];
    unsigned short h, l; split2(wv, h, l);
    wt1h[j] = h; wt1l[j] = l;
  } else if (idx < 81920) {
    int j = idx - 65536;
    int n = j >> 7, k = j & 127;
    float wv = (n < 64) ? Ws2[k * 64 + n] : Wn2[k * 64 + (n - 64)];
    unsigned short h, l; split2(wv, h, l);
    wt2h[j] = h; wt2l[j] = l;
  } else if (idx < 82048) {
    int c = idx - 81920;
    b2ext[c] = (c < 64) ? b2[c] : 0.0f;
  }
}

// ================= gather-mean -> packed bf16 hi/lo =================
// 64 lanes per node, float2 per lane. meanPk[n][c] = hi | (lo<<16).
__global__ __launch_bounds__(256) void gather_split(const float* __restrict__ h,
                                                    const int* __restrict__ cursor,
                                                    const int* __restrict__ csr,
                                                    unsigned* __restrict__ meanPk) {
  const int n = blockIdx.x * 4 + (threadIdx.x >> 6);
  const int lane = threadIdx.x & 63;
  const int end = cursor[n];
  const int start = (n == 0) ? 0 : cursor[n - 1];
  const float* hp = h + lane * 2;
  float ax = 0.f, ay = 0.f;
  int e = start;
  for (; e + 3 < end; e += 4) {
    int s0 = csr[e], s1 = csr[e + 1], s2 = csr[e + 2], s3 = csr[e + 3];
    float2 v0 = *(const float2*)(hp + (size_t)s0 * D);
    float2 v1 = *(const float2*)(hp + (size_t)s1 * D);
    float2 v2 = *(const float2*)(hp + (size_t)s2 * D);
    float2 v3 = *(const float2*)(hp + (size_t)s3 * D);
    ax += (v0.x + v1.x) + (v2.x + v3.x);
    ay += (v0.y + v1.y) + (v2.y + v3.y);
  }
  for (; e < end; ++e) {
    int s0 = csr[e];
    float2 v0 = *(const float2*)(hp + (size_t)s0 * D);
    ax += v0.x; ay += v0.y;
  }
  float inv = 1.0f / (float)max(end - start, 1);
  ax *= inv; ay *= inv;
  unsigned short hx, lx, hy, ly;
  split2(ax, hx, lx);
  split2(ay, hy, ly);
  uint2 pk;
  pk.x = (unsigned)hx | ((unsigned)lx << 16);
  pk.y = (unsigned)hy | ((unsigned)ly << 16);
  *(uint2*)(meanPk + (size_t)n * D + lane * 2) = pk;
}

// ================= bf16x3-split MFMA GEMM =================
// C[64 x 128] per block = [h | mean] @ WT^T via 16x16x32 bf16 MFMA, 3 products.
// QH: K-quarters (64 wide) from hsrc fp32 (split on the fly)
// QM: K-quarters from packed meanPk
template <int QH, int QM, int ACT, int SPLIT>
__global__ __launch_bounds__(256) void gemm_mfma(const float* __restrict__ hsrc,
                                                 const unsigned* __restrict__ meanPk,
                                                 const unsigned short* __restrict__ wth,
                                                 const unsigned short* __restrict__ wtl,
                                                 const float* __restrict__ bias,
                                                 float* __restrict__ out0,
                                                 float* __restrict__ out1) {
  constexpr int NQ = QH + QM;
  constexpr int K = NQ * 64;
  // 72-short row stride (144 B = 36 dwords, == 4 mod 32 banks -> uniform)
  __shared__ unsigned short aH[64][72];
  __shared__ unsigned short aL[64][72];
  const int tid = threadIdx.x;
  const int w = tid >> 6;
  const int l = tid & 63;
  const int lr = l & 15;  // fragment 16-index (m for A, n for B)
  const int lg = l >> 4;  // k-group
  const int row0 = blockIdx.x * 64;

  f32x4 acc[8];
#pragma unroll
  for (int i = 0; i < 8; ++i) acc[i] = (f32x4){0.f, 0.f, 0.f, 0.f};

  for (int q = 0; q < NQ; ++q) {
    __syncthreads();
    // stage 64 rows x 64 k of A (hi/lo) into LDS
#pragma unroll
    for (int i = 0; i < 4; ++i) {
      int idx = tid + i * 256;
      int r = idx >> 4;
      int c4 = (idx & 15) << 2;
      int node = min(row0 + r, N_NODES - 1);
      us4 hs, ls;
      if (q < QH) {
        float4 v = *(const float4*)(hsrc + (size_t)node * D + q * 64 + c4);
        unsigned short h0, l0, h1, l1, h2, l2, h3, l3;
        split2(v.x, h0, l0); split2(v.y, h1, l1);
        split2(v.z, h2, l2); split2(v.w, h3, l3);
        hs.x = h0; hs.y = h1; hs.z = h2; hs.w = h3;
        ls.x = l0; ls.y = l1; ls.z = l2; ls.w = l3;
      } else {
        uint4 p = *(const uint4*)(meanPk + (size_t)node * D + (q - QH) * 64 + c4);
        hs.x = (unsigned short)p.x; hs.y = (unsigned short)p.y;
        hs.z = (unsigned short)p.z; hs.w = (unsigned short)p.w;
        ls.x = (unsigned short)(p.x >> 16); ls.y = (unsigned short)(p.y >> 16);
        ls.z = (unsigned short)(p.z >> 16); ls.w = (unsigned short)(p.w >> 16);
      }
      *(us4*)&aH[r][c4] = hs;
      *(us4*)&aL[r][c4] = ls;
    }
    __syncthreads();
#pragma unroll
    for (int kt = 0; kt < 2; ++kt) {
      bf16x8 ah = *(const bf16x8*)&aH[w * 16 + lr][kt * 32 + lg * 8];
      bf16x8 al = *(const bf16x8*)&aL[w * 16 + lr][kt * 32 + lg * 8];
      const int kk = q * 64 + kt * 32 + lg * 8;
      const size_t bbase = (size_t)lr * K + kk;
#pragma unroll
      for (int nf = 0; nf < 8; ++nf) {
        bf16x8 bh = *(const bf16x8*)(wth + bbase + (size_t)nf * 16 * K);
        bf16x8 bl = *(const bf16x8*)(wtl + bbase + (size_t)nf * 16 * K);
        acc[nf] = __builtin_amdgcn_mfma_f32_16x16x32_bf16(ah, bh, acc[nf], 0, 0, 0);
        acc[nf] = __builtin_amdgcn_mfma_f32_16x16x32_bf16(al, bh, acc[nf], 0, 0, 0);
        acc[nf] = __builtin_amdgcn_mfma_f32_16x16x32_bf16(ah, bl, acc[nf], 0, 0, 0);
      }
    }
  }
  // epilogue: C row=(lg*4+i), col=lr (+16*nf)
#pragma unroll
  for (int nf = 0; nf < 8; ++nf) {
    const int col = nf * 16 + lr;
    const float bv = bias[col];
#pragma unroll
    for (int i = 0; i < 4; ++i) {
      const int grow = row0 + w * 16 + lg * 4 + i;
      if (grow < N_NODES) {
        float v = acc[nf][i] + bv;
        if (ACT) v = selu_f(v);
        if (SPLIT) {
          if (col < 64) out0[(size_t)grow * 64 + col] = v;
          else out1[(size_t)grow * 64 + (col - 64)] = v;
        } else {
          out0[(size_t)grow * D + col] = v;
        }
      }
    }
  }
}

// ================= fused gather(z) + add(u) + softmax =================
// 32 lanes per node, 2 cols per lane over the 64-wide z; u read from out, in-place softmax.
__global__ __launch_bounds__(256) void gather_sm(const float* __restrict__ zbuf,
                                                 const int* __restrict__ cursor,
                                                 const int* __restrict__ csr,
                                                 float* __restrict__ out) {
  const int n = blockIdx.x * 8 + (threadIdx.x >> 5);
  const int sl = threadIdx.x & 31;
  const int end = cursor[n];
  const int start = (n == 0) ? 0 : cursor[n - 1];
  const float* zp = zbuf + sl * 2;
  float ax = 0.f, ay = 0.f;
  int e = start;
  for (; e + 3 < end; e += 4) {
    int s0 = csr[e], s1 = csr[e + 1], s2 = csr[e + 2], s3 = csr[e + 3];
    float2 v0 = *(const float2*)(zp + (size_t)s0 * 64);
    float2 v1 = *(const float2*)(zp + (size_t)s1 * 64);
    float2 v2 = *(const float2*)(zp + (size_t)s2 * 64);
    float2 v3 = *(const float2*)(zp + (size_t)s3 * 64);
    ax += (v0.x + v1.x) + (v2.x + v3.x);
    ay += (v0.y + v1.y) + (v2.y + v3.y);
  }
  for (; e < end; ++e) {
    int s0 = csr[e];
    float2 v0 = *(const float2*)(zp + (size_t)s0 * 64);
    ax += v0.x; ay += v0.y;
  }
  float inv = 1.0f / (float)max(end - start, 1);
  size_t o = (size_t)n * 64 + sl * 2;
  float vx = out[o] + ax * inv;
  float vy = out[o + 1] + ay * inv;
  float m = fmaxf(vx, vy);
#pragma unroll
  for (int off = 16; off > 0; off >>= 1) m = fmaxf(m, __shfl_xor(m, off, 64));
  float ex = expf(vx - m);
  float ey = expf(vy - m);
  float s = ex + ey;
#pragma unroll
  for (int off = 16; off > 0; off >>= 1) s += __shfl_xor(s, off, 64);
  float r = 1.0f / s;
  out[o] = ex * r;
  out[o + 1] = ey * r;
}

extern "C" void kernel_launch(void* const* d_in, const int* in_sizes, int n_in,
                              void* d_out, int out_size, void* d_ws, size_t ws_size,
                              hipStream_t stream) {
  const float* x   = (const float*)d_in[0];
  const int* src   = (const int*)d_in[1];
  const int* dst   = (const int*)d_in[2];
  const float* Ws0 = (const float*)d_in[3];
  const float* Wn0 = (const float*)d_in[4];
  const float* b0  = (const float*)d_in[5];
  const float* Ws1 = (const float*)d_in[6];
  const float* Wn1 = (const float*)d_in[7];
  const float* b1  = (const float*)d_in[8];
  const float* Ws2 = (const float*)d_in[9];
  const float* Wn2 = (const float*)d_in[10];
  const float* b2  = (const float*)d_in[11];
  float* out = (float*)d_out;

  // ws layout (same 80.2 MB footprint proven in round 2):
  //   cursor int[50048] | csr int[800000] | A=h1 25.6MB | B=h2 25.6MB | C 25.6MB
  // C region: cnt (CSR build) -> meanPk (layers 0/1) -> zbuf (layer 2)
  char* ws = (char*)d_ws;
  int* cursor = (int*)ws;
  int* csr    = (int*)(ws + 200192);
  float* h1   = (float*)(ws + 3400192);
  float* h2   = (float*)(ws + 29000192);
  char* Creg  = ws + 54600192;
  unsigned* meanPk = (unsigned*)Creg;
  float* zbuf      = (float*)Creg;
  int* cnt         = (int*)Creg;

  // split weights staged in d_out (12.8 MB; overwritten by layer-2 output later)
  unsigned short* W = (unsigned short*)d_out;
  unsigned short* wt0h = W;
  unsigned short* wt0l = W + 32768;
  unsigned short* wt1h = W + 65536;
  unsigned short* wt1l = W + 98304;
  unsigned short* wt2h = W + 131072;
  unsigned short* wt2l = W + 147456;
  float* b2ext = (float*)(W + 163840);

  // layer-2 weight copy target: A region (h1 is dead by then)
  unsigned short* wt2hc = (unsigned short*)h1;
  unsigned short* wt2lc = wt2hc + 16384;
  float* b2extc = (float*)(wt2hc + 32768);

  // CSR build
  hipMemsetAsync(cnt, 0, N_NODES * sizeof(int), stream);
  hist_kernel<<<3125, 256, 0, stream>>>(dst, cnt);
  scan_kernel<<<1, 1024, 0, stream>>>(cnt, cursor);
  fill_kernel<<<3125, 256, 0, stream>>>(src, dst, cursor, csr);
  wsplit_kernel<<<321, 256, 0, stream>>>(Ws0, Wn0, Ws1, Wn1, Ws2, Wn2, b2,
                                         wt0h, wt0l, wt1h, wt1l, wt2h, wt2l, b2ext);

  // layer 0: x -> h1 (selu)
  gather_split<<<12500, 256, 0, stream>>>(x, cursor, csr, meanPk);
  gemm_mfma<2, 2, 1, 0><<<782, 256, 0, stream>>>(x, meanPk, wt0h, wt0l, b0, h1, nullptr);

  // layer 1: h1 -> h2 (selu)
  gather_split<<<12500, 256, 0, stream>>>(h1, cursor, csr, meanPk);
  gemm_mfma<2, 2, 1, 0><<<782, 256, 0, stream>>>(h1, meanPk, wt1h, wt1l, b1, h2, nullptr);

  // layer 2: u = h2@Ws2 + b2 -> out ; z = h2@Wn2 -> zbuf ; then mean(z) + u -> softmax
  hipMemcpyAsync(wt2hc, wt2h, 66048, hipMemcpyDeviceToDevice, stream);
  gemm_mfma<2, 0, 0, 1><<<782, 256, 0, stream>>>(h2, nullptr, wt2hc, wt2lc, b2extc, out, zbuf);
  gather_sm<<<6250, 256, 0, stream>>>(zbuf, cursor, csr, out);
}

// Round 4
// 468.584 us; speedup vs baseline: 9.8157x; 1.1821x over previous
//
#include <hip/hip_runtime.h>
#include <hip/hip_bf16.h>

#define N_NODES 50000
#define N_EDGES 800000
#define D 128
#define SCAN_B 196  // ceil(N_NODES/256)

typedef __attribute__((ext_vector_type(8))) __bf16 bf16x8;
typedef __attribute__((ext_vector_type(4))) float f32x4;
typedef __attribute__((ext_vector_type(4))) unsigned short us4;

// ---- fp32 -> bf16 split helpers (RNE) ----
__device__ __forceinline__ unsigned short bf16_rne(float x) {
  unsigned u = __builtin_bit_cast(unsigned, x);
  unsigned r = u + 0x7fffu + ((u >> 16) & 1u);
  return (unsigned short)(r >> 16);
}
__device__ __forceinline__ float bf16_f(unsigned short b) {
  unsigned u = ((unsigned)b) << 16;
  return __builtin_bit_cast(float, u);
}
__device__ __forceinline__ void split2(float x, unsigned short& hi, unsigned short& lo) {
  hi = bf16_rne(x);
  lo = bf16_rne(x - bf16_f(hi));
}

__device__ __forceinline__ float selu_f(float x) {
  const float alpha = 1.6732632423543772f;
  const float scale = 1.0507009873554805f;
  return scale * (x > 0.0f ? x : alpha * expm1f(x));
}

// ================= CSR build =================
__global__ __launch_bounds__(256) void hist_kernel(const int* __restrict__ dst,
                                                   int* __restrict__ cnt) {
  int e = blockIdx.x * 256 + threadIdx.x;
  if (e < N_EDGES) atomicAdd(&cnt[dst[e]], 1);
}

// --- 2-level parallel exclusive scan ---
// scan1: per-block Hillis-Steele; write exclusive partials + block sum
__global__ __launch_bounds__(256) void scan1_kernel(const int* __restrict__ cnt,
                                                    int* __restrict__ cursor,
                                                    int* __restrict__ bsum) {
  __shared__ int s[256];
  const int t = threadIdx.x;
  const int i = blockIdx.x * 256 + t;
  int v = (i < N_NODES) ? cnt[i] : 0;
  s[t] = v;
  __syncthreads();
#pragma unroll
  for (int off = 1; off < 256; off <<= 1) {
    int u = (t >= off) ? s[t - off] : 0;
    __syncthreads();
    s[t] += u;
    __syncthreads();
  }
  if (i < N_NODES) cursor[i] = s[t] - v;  // exclusive, missing block offset
  if (t == 255) bsum[blockIdx.x] = s[255];
}

// scan2: scan the block sums (SCAN_B <= 256), write exclusive block offsets
__global__ __launch_bounds__(256) void scan2_kernel(int* __restrict__ bsum) {
  __shared__ int s[256];
  const int t = threadIdx.x;
  int v = (t < SCAN_B) ? bsum[t] : 0;
  s[t] = v;
  __syncthreads();
#pragma unroll
  for (int off = 1; off < 256; off <<= 1) {
    int u = (t >= off) ? s[t - off] : 0;
    __syncthreads();
    s[t] += u;
    __syncthreads();
  }
  if (t < SCAN_B) bsum[t] = s[t] - v;  // exclusive
}

// scan3: add block offsets
__global__ __launch_bounds__(256) void scan3_kernel(int* __restrict__ cursor,
                                                    const int* __restrict__ bsum) {
  const int i = blockIdx.x * 256 + threadIdx.x;
  if (i < N_NODES) cursor[i] += bsum[blockIdx.x];
}

// fill: cursor[n] goes from start offset -> end offset as edges append
__global__ __launch_bounds__(256) void fill_kernel(const int* __restrict__ src,
                                                   const int* __restrict__ dst,
                                                   int* __restrict__ cursor,
                                                   int* __restrict__ csr_src) {
  int e = blockIdx.x * 256 + threadIdx.x;
  if (e < N_EDGES) {
    int pos = atomicAdd(&cursor[dst[e]], 1);
    csr_src[pos] = src[e];
  }
}

// ================= weight split/transpose precompute =================
__global__ __launch_bounds__(256) void wsplit_kernel(
    const float* __restrict__ Ws0, const float* __restrict__ Wn0,
    const float* __restrict__ Ws1, const float* __restrict__ Wn1,
    const float* __restrict__ Ws2, const float* __restrict__ Wn2,
    const float* __restrict__ b2,
    unsigned short* __restrict__ wt0h, unsigned short* __restrict__ wt0l,
    unsigned short* __restrict__ wt1h, unsigned short* __restrict__ wt1l,
    unsigned short* __restrict__ wt2h, unsigned short* __restrict__ wt2l,
    float* __restrict__ b2ext) {
  int idx = blockIdx.x * 256 + threadIdx.x;
  if (idx < 32768) {
    int n = idx >> 8, k = idx & 255;
    float wv = (k < 128) ? Ws0[k * 128 + n] : Wn0[(k - 128) * 128 + n];
    unsigned short h, l; split2(wv, h, l);
    wt0h[idx] = h; wt0l[idx] = l;
  } else if (idx < 65536) {
    int j = idx - 32768;
    int n = j >> 8, k = j & 255;
    float wv = (k < 128) ? Ws1[k * 128 + n] : Wn1[(k - 128) * 128 + n];
    unsigned short h, l; split2(wv, h, l);
    wt1h[j] = h; wt1l[j] = l;
  } else if (idx < 81920) {
    int j = idx - 65536;
    int n = j >> 7, k = j & 127;
    float wv = (n < 64) ? Ws2[k * 64 + n] : Wn2[k * 64 + (n - 64)];
    unsigned short h, l; split2(wv, h, l);
    wt2h[j] = h; wt2l[j] = l;
  } else if (idx < 82048) {
    int c = idx - 81920;
    b2ext[c] = (c < 64) ? b2[c] : 0.0f;
  }
}

// ================= gather-mean -> packed bf16 hi/lo =================
__global__ __launch_bounds__(256) void gather_split(const float* __restrict__ h,
                                                    const int* __restrict__ cursor,
                                                    const int* __restrict__ csr,
                                                    unsigned* __restrict__ meanPk) {
  const int n = blockIdx.x * 4 + (threadIdx.x >> 6);
  const int lane = threadIdx.x & 63;
  const int end = cursor[n];
  const int start = (n == 0) ? 0 : cursor[n - 1];
  const float* hp = h + lane * 2;
  float ax = 0.f, ay = 0.f;
  int e = start;
  for (; e + 3 < end; e += 4) {
    int s0 = csr[e], s1 = csr[e + 1], s2 = csr[e + 2], s3 = csr[e + 3];
    float2 v0 = *(const float2*)(hp + (size_t)s0 * D);
    float2 v1 = *(const float2*)(hp + (size_t)s1 * D);
    float2 v2 = *(const float2*)(hp + (size_t)s2 * D);
    float2 v3 = *(const float2*)(hp + (size_t)s3 * D);
    ax += (v0.x + v1.x) + (v2.x + v3.x);
    ay += (v0.y + v1.y) + (v2.y + v3.y);
  }
  for (; e < end; ++e) {
    int s0 = csr[e];
    float2 v0 = *(const float2*)(hp + (size_t)s0 * D);
    ax += v0.x; ay += v0.y;
  }
  float inv = 1.0f / (float)max(end - start, 1);
  ax *= inv; ay *= inv;
  unsigned short hx, lx, hy, ly;
  split2(ax, hx, lx);
  split2(ay, hy, ly);
  uint2 pk;
  pk.x = (unsigned)hx | ((unsigned)lx << 16);
  pk.y = (unsigned)hy | ((unsigned)ly << 16);
  *(uint2*)(meanPk + (size_t)n * D + lane * 2) = pk;
}

// ================= bf16x3-split MFMA GEMM =================
template <int QH, int QM, int ACT, int SPLIT>
__global__ __launch_bounds__(256) void gemm_mfma(const float* __restrict__ hsrc,
                                                 const unsigned* __restrict__ meanPk,
                                                 const unsigned short* __restrict__ wth,
                                                 const unsigned short* __restrict__ wtl,
                                                 const float* __restrict__ bias,
                                                 float* __restrict__ out0,
                                                 float* __restrict__ out1) {
  constexpr int NQ = QH + QM;
  constexpr int K = NQ * 64;
  __shared__ unsigned short aH[64][72];
  __shared__ unsigned short aL[64][72];
  const int tid = threadIdx.x;
  const int w = tid >> 6;
  const int l = tid & 63;
  const int lr = l & 15;
  const int lg = l >> 4;
  const int row0 = blockIdx.x * 64;

  f32x4 acc[8];
#pragma unroll
  for (int i = 0; i < 8; ++i) acc[i] = (f32x4){0.f, 0.f, 0.f, 0.f};

  for (int q = 0; q < NQ; ++q) {
    __syncthreads();
#pragma unroll
    for (int i = 0; i < 4; ++i) {
      int idx = tid + i * 256;
      int r = idx >> 4;
      int c4 = (idx & 15) << 2;
      int node = min(row0 + r, N_NODES - 1);
      us4 hs, ls;
      if (q < QH) {
        float4 v = *(const float4*)(hsrc + (size_t)node * D + q * 64 + c4);
        unsigned short h0, l0, h1, l1, h2, l2, h3, l3;
        split2(v.x, h0, l0); split2(v.y, h1, l1);
        split2(v.z, h2, l2); split2(v.w, h3, l3);
        hs.x = h0; hs.y = h1; hs.z = h2; hs.w = h3;
        ls.x = l0; ls.y = l1; ls.z = l2; ls.w = l3;
      } else {
        uint4 p = *(const uint4*)(meanPk + (size_t)node * D + (q - QH) * 64 + c4);
        hs.x = (unsigned short)p.x; hs.y = (unsigned short)p.y;
        hs.z = (unsigned short)p.z; hs.w = (unsigned short)p.w;
        ls.x = (unsigned short)(p.x >> 16); ls.y = (unsigned short)(p.y >> 16);
        ls.z = (unsigned short)(p.z >> 16); ls.w = (unsigned short)(p.w >> 16);
      }
      *(us4*)&aH[r][c4] = hs;
      *(us4*)&aL[r][c4] = ls;
    }
    __syncthreads();
#pragma unroll
    for (int kt = 0; kt < 2; ++kt) {
      bf16x8 ah = *(const bf16x8*)&aH[w * 16 + lr][kt * 32 + lg * 8];
      bf16x8 al = *(const bf16x8*)&aL[w * 16 + lr][kt * 32 + lg * 8];
      const int kk = q * 64 + kt * 32 + lg * 8;
      const size_t bbase = (size_t)lr * K + kk;
#pragma unroll
      for (int nf = 0; nf < 8; ++nf) {
        bf16x8 bh = *(const bf16x8*)(wth + bbase + (size_t)nf * 16 * K);
        bf16x8 bl = *(const bf16x8*)(wtl + bbase + (size_t)nf * 16 * K);
        acc[nf] = __builtin_amdgcn_mfma_f32_16x16x32_bf16(ah, bh, acc[nf], 0, 0, 0);
        acc[nf] = __builtin_amdgcn_mfma_f32_16x16x32_bf16(al, bh, acc[nf], 0, 0, 0);
        acc[nf] = __builtin_amdgcn_mfma_f32_16x16x32_bf16(ah, bl, acc[nf], 0, 0, 0);
      }
    }
  }
#pragma unroll
  for (int nf = 0; nf < 8; ++nf) {
    const int col = nf * 16 + lr;
    const float bv = bias[col];
#pragma unroll
    for (int i = 0; i < 4; ++i) {
      const int grow = row0 + w * 16 + lg * 4 + i;
      if (grow < N_NODES) {
        float v = acc[nf][i] + bv;
        if (ACT) v = selu_f(v);
        if (SPLIT) {
          if (col < 64) out0[(size_t)grow * 64 + col] = v;
          else out1[(size_t)grow * 64 + (col - 64)] = v;
        } else {
          out0[(size_t)grow * D + col] = v;
        }
      }
    }
  }
}

// ================= fused gather(z) + add(u) + softmax =================
__global__ __launch_bounds__(256) void gather_sm(const float* __restrict__ zbuf,
                                                 const int* __restrict__ cursor,
                                                 const int* __restrict__ csr,
                                                 float* __restrict__ out) {
  const int n = blockIdx.x * 8 + (threadIdx.x >> 5);
  const int sl = threadIdx.x & 31;
  const int end = cursor[n];
  const int start = (n == 0) ? 0 : cursor[n - 1];
  const float* zp = zbuf + sl * 2;
  float ax = 0.f, ay = 0.f;
  int e = start;
  for (; e + 3 < end; e += 4) {
    int s0 = csr[e], s1 = csr[e + 1], s2 = csr[e + 2], s3 = csr[e + 3];
    float2 v0 = *(const float2*)(zp + (size_t)s0 * 64);
    float2 v1 = *(const float2*)(zp + (size_t)s1 * 64);
    float2 v2 = *(const float2*)(zp + (size_t)s2 * 64);
    float2 v3 = *(const float2*)(zp + (size_t)s3 * 64);
    ax += (v0.x + v1.x) + (v2.x + v3.x);
    ay += (v0.y + v1.y) + (v2.y + v3.y);
  }
  for (; e < end; ++e) {
    int s0 = csr[e];
    float2 v0 = *(const float2*)(zp + (size_t)s0 * 64);
    ax += v0.x; ay += v0.y;
  }
  float inv = 1.0f / (float)max(end - start, 1);
  size_t o = (size_t)n * 64 + sl * 2;
  float vx = out[o] + ax * inv;
  float vy = out[o + 1] + ay * inv;
  float m = fmaxf(vx, vy);
#pragma unroll
  for (int off = 16; off > 0; off >>= 1) m = fmaxf(m, __shfl_xor(m, off, 64));
  float ex = expf(vx - m);
  float ey = expf(vy - m);
  float s = ex + ey;
#pragma unroll
  for (int off = 16; off > 0; off >>= 1) s += __shfl_xor(s, off, 64);
  float r = 1.0f / s;
  out[o] = ex * r;
  out[o + 1] = ey * r;
}

extern "C" void kernel_launch(void* const* d_in, const int* in_sizes, int n_in,
                              void* d_out, int out_size, void* d_ws, size_t ws_size,
                              hipStream_t stream) {
  const float* x   = (const float*)d_in[0];
  const int* src   = (const int*)d_in[1];
  const int* dst   = (const int*)d_in[2];
  const float* Ws0 = (const float*)d_in[3];
  const float* Wn0 = (const float*)d_in[4];
  const float* b0  = (const float*)d_in[5];
  const float* Ws1 = (const float*)d_in[6];
  const float* Wn1 = (const float*)d_in[7];
  const float* b1  = (const float*)d_in[8];
  const float* Ws2 = (const float*)d_in[9];
  const float* Wn2 = (const float*)d_in[10];
  const float* b2  = (const float*)d_in[11];
  float* out = (float*)d_out;

  // ws layout: cursor int[50048] | csr int[800000] | A=h1 25.6MB | B=h2 25.6MB | C 25.6MB
  char* ws = (char*)d_ws;
  int* cursor = (int*)ws;
  int* csr    = (int*)(ws + 200192);
  float* h1   = (float*)(ws + 3400192);
  float* h2   = (float*)(ws + 29000192);
  char* Creg  = ws + 54600192;
  unsigned* meanPk = (unsigned*)Creg;
  float* zbuf      = (float*)Creg;
  int* cnt         = (int*)Creg;
  int* bsum        = (int*)(Creg + N_NODES * sizeof(int));  // SCAN_B ints

  // split weights staged in d_out (12.8 MB; overwritten by layer-2 output later)
  unsigned short* W = (unsigned short*)d_out;
  unsigned short* wt0h = W;
  unsigned short* wt0l = W + 32768;
  unsigned short* wt1h = W + 65536;
  unsigned short* wt1l = W + 98304;
  unsigned short* wt2h = W + 131072;
  unsigned short* wt2l = W + 147456;
  float* b2ext = (float*)(W + 163840);

  // layer-2 weight copy target: A region (h1 is dead by then)
  unsigned short* wt2hc = (unsigned short*)h1;
  unsigned short* wt2lc = wt2hc + 16384;
  float* b2extc = (float*)(wt2hc + 32768);

  // CSR build (parallel 2-level scan)
  hipMemsetAsync(cnt, 0, N_NODES * sizeof(int), stream);
  hist_kernel<<<3125, 256, 0, stream>>>(dst, cnt);
  scan1_kernel<<<SCAN_B, 256, 0, stream>>>(cnt, cursor, bsum);
  scan2_kernel<<<1, 256, 0, stream>>>(bsum);
  scan3_kernel<<<SCAN_B, 256, 0, stream>>>(cursor, bsum);
  fill_kernel<<<3125, 256, 0, stream>>>(src, dst, cursor, csr);
  wsplit_kernel<<<321, 256, 0, stream>>>(Ws0, Wn0, Ws1, Wn1, Ws2, Wn2, b2,
                                         wt0h, wt0l, wt1h, wt1l, wt2h, wt2l, b2ext);

  // layer 0: x -> h1 (selu)
  gather_split<<<12500, 256, 0, stream>>>(x, cursor, csr, meanPk);
  gemm_mfma<2, 2, 1, 0><<<782, 256, 0, stream>>>(x, meanPk, wt0h, wt0l, b0, h1, nullptr);

  // layer 1: h1 -> h2 (selu)
  gather_split<<<12500, 256, 0, stream>>>(h1, cursor, csr, meanPk);
  gemm_mfma<2, 2, 1, 0><<<782, 256, 0, stream>>>(h1, meanPk, wt1h, wt1l, b1, h2, nullptr);

  // layer 2: u = h2@Ws2 + b2 -> out ; z = h2@Wn2 -> zbuf ; then mean(z) + u -> softmax
  hipMemcpyAsync(wt2hc, wt2h, 66048, hipMemcpyDeviceToDevice, stream);
  gemm_mfma<2, 0, 0, 1><<<782, 256, 0, stream>>>(h2, nullptr, wt2hc, wt2lc, b2extc, out, zbuf);
  gather_sm<<<6250, 256, 0, stream>>>(zbuf, cursor, csr, out);
}

// Round 5
// 442.921 us; speedup vs baseline: 10.3844x; 1.0579x over previous
//
#include <hip/hip_runtime.h>
#include <hip/hip_bf16.h>

#define N_NODES 50000
#define N_EDGES 800000
#define D 128
#define SCAN_B 196  // ceil(N_NODES/256)

typedef __attribute__((ext_vector_type(8))) __bf16 bf16x8;
typedef __attribute__((ext_vector_type(4))) float f32x4;

union U8 {
  bf16x8 v;
  uint4 u;
};

// ---- fp32 -> bf16 split helpers (RNE; used in precompute/gather) ----
__device__ __forceinline__ unsigned short bf16_rne(float x) {
  unsigned u = __builtin_bit_cast(unsigned, x);
  unsigned r = u + 0x7fffu + ((u >> 16) & 1u);
  return (unsigned short)(r >> 16);
}
__device__ __forceinline__ float bf16_f(unsigned short b) {
  unsigned u = ((unsigned)b) << 16;
  return __builtin_bit_cast(float, u);
}
__device__ __forceinline__ void split2(float x, unsigned short& hi, unsigned short& lo) {
  hi = bf16_rne(x);
  lo = bf16_rne(x - bf16_f(hi));
}

__device__ __forceinline__ float selu_f(float x) {
  const float alpha = 1.6732632423543772f;
  const float scale = 1.0507009873554805f;
  return scale * (x > 0.0f ? x : alpha * expm1f(x));
}

// ================= CSR build =================
__global__ __launch_bounds__(256) void hist_kernel(const int* __restrict__ dst,
                                                   int* __restrict__ cnt) {
  int e = blockIdx.x * 256 + threadIdx.x;
  if (e < N_EDGES) atomicAdd(&cnt[dst[e]], 1);
}

__global__ __launch_bounds__(256) void scan1_kernel(const int* __restrict__ cnt,
                                                    int* __restrict__ cursor,
                                                    int* __restrict__ bsum) {
  __shared__ int s[256];
  const int t = threadIdx.x;
  const int i = blockIdx.x * 256 + t;
  int v = (i < N_NODES) ? cnt[i] : 0;
  s[t] = v;
  __syncthreads();
#pragma unroll
  for (int off = 1; off < 256; off <<= 1) {
    int u = (t >= off) ? s[t - off] : 0;
    __syncthreads();
    s[t] += u;
    __syncthreads();
  }
  if (i < N_NODES) cursor[i] = s[t] - v;
  if (t == 255) bsum[blockIdx.x] = s[255];
}

__global__ __launch_bounds__(256) void scan2_kernel(int* __restrict__ bsum) {
  __shared__ int s[256];
  const int t = threadIdx.x;
  int v = (t < SCAN_B) ? bsum[t] : 0;
  s[t] = v;
  __syncthreads();
#pragma unroll
  for (int off = 1; off < 256; off <<= 1) {
    int u = (t >= off) ? s[t - off] : 0;
    __syncthreads();
    s[t] += u;
    __syncthreads();
  }
  if (t < SCAN_B) bsum[t] = s[t] - v;
}

__global__ __launch_bounds__(256) void scan3_kernel(int* __restrict__ cursor,
                                                    const int* __restrict__ bsum) {
  const int i = blockIdx.x * 256 + threadIdx.x;
  if (i < N_NODES) cursor[i] += bsum[blockIdx.x];
}

__global__ __launch_bounds__(256) void fill_kernel(const int* __restrict__ src,
                                                   const int* __restrict__ dst,
                                                   int* __restrict__ cursor,
                                                   int* __restrict__ csr_src) {
  int e = blockIdx.x * 256 + threadIdx.x;
  if (e < N_EDGES) {
    int pos = atomicAdd(&cursor[dst[e]], 1);
    csr_src[pos] = src[e];
  }
}

// ================= weight split/transpose precompute =================
__global__ __launch_bounds__(256) void wsplit_kernel(
    const float* __restrict__ Ws0, const float* __restrict__ Wn0,
    const float* __restrict__ Ws1, const float* __restrict__ Wn1,
    const float* __restrict__ Ws2, const float* __restrict__ Wn2,
    const float* __restrict__ b2,
    unsigned short* __restrict__ wt0h, unsigned short* __restrict__ wt0l,
    unsigned short* __restrict__ wt1h, unsigned short* __restrict__ wt1l,
    unsigned short* __restrict__ wt2h, unsigned short* __restrict__ wt2l,
    float* __restrict__ b2ext) {
  int idx = blockIdx.x * 256 + threadIdx.x;
  if (idx < 32768) {
    int n = idx >> 8, k = idx & 255;
    float wv = (k < 128) ? Ws0[k * 128 + n] : Wn0[(k - 128) * 128 + n];
    unsigned short h, l; split2(wv, h, l);
    wt0h[idx] = h; wt0l[idx] = l;
  } else if (idx < 65536) {
    int j = idx - 32768;
    int n = j >> 8, k = j & 255;
    float wv = (k < 128) ? Ws1[k * 128 + n] : Wn1[(k - 128) * 128 + n];
    unsigned short h, l; split2(wv, h, l);
    wt1h[j] = h; wt1l[j] = l;
  } else if (idx < 81920) {
    int j = idx - 65536;
    int n = j >> 7, k = j & 127;
    float wv = (n < 64) ? Ws2[k * 64 + n] : Wn2[k * 64 + (n - 64)];
    unsigned short h, l; split2(wv, h, l);
    wt2h[j] = h; wt2l[j] = l;
  } else if (idx < 82048) {
    int c = idx - 81920;
    b2ext[c] = (c < 64) ? b2[c] : 0.0f;
  }
}

// ================= gather-mean -> packed bf16 hi/lo =================
__global__ __launch_bounds__(256) void gather_split(const float* __restrict__ h,
                                                    const int* __restrict__ cursor,
                                                    const int* __restrict__ csr,
                                                    unsigned* __restrict__ meanPk) {
  const int n = blockIdx.x * 4 + (threadIdx.x >> 6);
  const int lane = threadIdx.x & 63;
  const int end = cursor[n];
  const int start = (n == 0) ? 0 : cursor[n - 1];
  const float* hp = h + lane * 2;
  float ax = 0.f, ay = 0.f;
  int e = start;
  for (; e + 3 < end; e += 4) {
    int s0 = csr[e], s1 = csr[e + 1], s2 = csr[e + 2], s3 = csr[e + 3];
    float2 v0 = *(const float2*)(hp + (size_t)s0 * D);
    float2 v1 = *(const float2*)(hp + (size_t)s1 * D);
    float2 v2 = *(const float2*)(hp + (size_t)s2 * D);
    float2 v3 = *(const float2*)(hp + (size_t)s3 * D);
    ax += (v0.x + v1.x) + (v2.x + v3.x);
    ay += (v0.y + v1.y) + (v2.y + v3.y);
  }
  for (; e < end; ++e) {
    int s0 = csr[e];
    float2 v0 = *(const float2*)(hp + (size_t)s0 * D);
    ax += v0.x; ay += v0.y;
  }
  float inv = 1.0f / (float)max(end - start, 1);
  ax *= inv; ay *= inv;
  unsigned short hx, lx, hy, ly;
  split2(ax, hx, lx);
  split2(ay, hy, ly);
  uint2 pk;
  pk.x = (unsigned)hx | ((unsigned)lx << 16);
  pk.y = (unsigned)hy | ((unsigned)ly << 16);
  *(uint2*)(meanPk + (size_t)n * D + lane * 2) = pk;
}

// ================= bf16x3-split MFMA GEMM, barrier-free, LDS-free =================
// Each wave owns a 16-row x 128-col tile; A fragments loaded per-lane from global
// (fp32 trunc-split or packed mean), B streamed from split weights (L2-resident).
template <int QH, int QM, int ACT, int SPLIT>
__global__ __launch_bounds__(256) void gemm_direct(const float* __restrict__ hsrc,
                                                   const unsigned* __restrict__ meanPk,
                                                   const unsigned short* __restrict__ wth,
                                                   const unsigned short* __restrict__ wtl,
                                                   const float* __restrict__ bias,
                                                   float* __restrict__ out0,
                                                   float* __restrict__ out1) {
  constexpr int NQ = QH + QM;
  constexpr int K = NQ * 64;
  const int tid = threadIdx.x;
  const int w = tid >> 6;
  const int l = tid & 63;
  const int lr = l & 15;
  const int lg = l >> 4;
  const int row0 = blockIdx.x * 64;
  const int grow0 = row0 + w * 16 + lr;
  const int arow = min(grow0, N_NODES - 1);

  const float* ap = hsrc + (size_t)arow * D;
  const unsigned* mp = meanPk + (size_t)arow * D;
  const unsigned short* bhp = wth + (size_t)lr * K;
  const unsigned short* blp = wtl + (size_t)lr * K;

  f32x4 acc[8];
#pragma unroll
  for (int i = 0; i < 8; ++i) acc[i] = (f32x4){0.f, 0.f, 0.f, 0.f};

#pragma unroll
  for (int q = 0; q < NQ; ++q) {
#pragma unroll
    for (int kt = 0; kt < 2; ++kt) {
      const int k0 = q * 64 + kt * 32 + lg * 8;
      U8 ah, al;
      if (q < QH) {
        float4 v0 = *(const float4*)(ap + k0);
        float4 v1 = *(const float4*)(ap + k0 + 4);
        unsigned u0 = __builtin_bit_cast(unsigned, v0.x);
        unsigned u1 = __builtin_bit_cast(unsigned, v0.y);
        unsigned u2 = __builtin_bit_cast(unsigned, v0.z);
        unsigned u3 = __builtin_bit_cast(unsigned, v0.w);
        unsigned u4 = __builtin_bit_cast(unsigned, v1.x);
        unsigned u5 = __builtin_bit_cast(unsigned, v1.y);
        unsigned u6 = __builtin_bit_cast(unsigned, v1.z);
        unsigned u7 = __builtin_bit_cast(unsigned, v1.w);
        ah.u.x = (u0 >> 16) | (u1 & 0xffff0000u);
        ah.u.y = (u2 >> 16) | (u3 & 0xffff0000u);
        ah.u.z = (u4 >> 16) | (u5 & 0xffff0000u);
        ah.u.w = (u6 >> 16) | (u7 & 0xffff0000u);
        unsigned r0 = __builtin_bit_cast(unsigned, v0.x - __builtin_bit_cast(float, u0 & 0xffff0000u));
        unsigned r1 = __builtin_bit_cast(unsigned, v0.y - __builtin_bit_cast(float, u1 & 0xffff0000u));
        unsigned r2 = __builtin_bit_cast(unsigned, v0.z - __builtin_bit_cast(float, u2 & 0xffff0000u));
        unsigned r3 = __builtin_bit_cast(unsigned, v0.w - __builtin_bit_cast(float, u3 & 0xffff0000u));
        unsigned r4 = __builtin_bit_cast(unsigned, v1.x - __builtin_bit_cast(float, u4 & 0xffff0000u));
        unsigned r5 = __builtin_bit_cast(unsigned, v1.y - __builtin_bit_cast(float, u5 & 0xffff0000u));
        unsigned r6 = __builtin_bit_cast(unsigned, v1.z - __builtin_bit_cast(float, u6 & 0xffff0000u));
        unsigned r7 = __builtin_bit_cast(unsigned, v1.w - __builtin_bit_cast(float, u7 & 0xffff0000u));
        al.u.x = (r0 >> 16) | (r1 & 0xffff0000u);
        al.u.y = (r2 >> 16) | (r3 & 0xffff0000u);
        al.u.z = (r4 >> 16) | (r5 & 0xffff0000u);
        al.u.w = (r6 >> 16) | (r7 & 0xffff0000u);
      } else {
        const int c0 = (q - QH) * 64 + kt * 32 + lg * 8;
        uint4 p0 = *(const uint4*)(mp + c0);
        uint4 p1 = *(const uint4*)(mp + c0 + 4);
        ah.u.x = (p0.x & 0xffffu) | (p0.y << 16);
        ah.u.y = (p0.z & 0xffffu) | (p0.w << 16);
        ah.u.z = (p1.x & 0xffffu) | (p1.y << 16);
        ah.u.w = (p1.z & 0xffffu) | (p1.w << 16);
        al.u.x = (p0.x >> 16) | (p0.y & 0xffff0000u);
        al.u.y = (p0.z >> 16) | (p0.w & 0xffff0000u);
        al.u.z = (p1.x >> 16) | (p1.y & 0xffff0000u);
        al.u.w = (p1.z >> 16) | (p1.w & 0xffff0000u);
      }
#pragma unroll
      for (int nf = 0; nf < 8; ++nf) {
        bf16x8 bh = *(const bf16x8*)(bhp + (size_t)nf * 16 * K + k0);
        bf16x8 bl = *(const bf16x8*)(blp + (size_t)nf * 16 * K + k0);
        acc[nf] = __builtin_amdgcn_mfma_f32_16x16x32_bf16(ah.v, bh, acc[nf], 0, 0, 0);
        acc[nf] = __builtin_amdgcn_mfma_f32_16x16x32_bf16(al.v, bh, acc[nf], 0, 0, 0);
        acc[nf] = __builtin_amdgcn_mfma_f32_16x16x32_bf16(ah.v, bl, acc[nf], 0, 0, 0);
      }
    }
  }
  // epilogue: C col = lr (+16*nf), row = lg*4 + i (within wave's 16 rows)
#pragma unroll
  for (int nf = 0; nf < 8; ++nf) {
    const int col = nf * 16 + lr;
    const float bv = bias[col];
#pragma unroll
    for (int i = 0; i < 4; ++i) {
      const int grow = row0 + w * 16 + lg * 4 + i;
      if (grow < N_NODES) {
        float v = acc[nf][i] + bv;
        if (ACT) v = selu_f(v);
        if (SPLIT) {
          if (col < 64) out0[(size_t)grow * 64 + col] = v;
          else out1[(size_t)grow * 64 + (col - 64)] = v;
        } else {
          out0[(size_t)grow * D + col] = v;
        }
      }
    }
  }
}

// ================= fused gather(z) + add(u) + softmax =================
__global__ __launch_bounds__(256) void gather_sm(const float* __restrict__ zbuf,
                                                 const int* __restrict__ cursor,
                                                 const int* __restrict__ csr,
                                                 float* __restrict__ out) {
  const int n = blockIdx.x * 8 + (threadIdx.x >> 5);
  const int sl = threadIdx.x & 31;
  const int end = cursor[n];
  const int start = (n == 0) ? 0 : cursor[n - 1];
  const float* zp = zbuf + sl * 2;
  float ax = 0.f, ay = 0.f;
  int e = start;
  for (; e + 3 < end; e += 4) {
    int s0 = csr[e], s1 = csr[e + 1], s2 = csr[e + 2], s3 = csr[e + 3];
    float2 v0 = *(const float2*)(zp + (size_t)s0 * 64);
    float2 v1 = *(const float2*)(zp + (size_t)s1 * 64);
    float2 v2 = *(const float2*)(zp + (size_t)s2 * 64);
    float2 v3 = *(const float2*)(zp + (size_t)s3 * 64);
    ax += (v0.x + v1.x) + (v2.x + v3.x);
    ay += (v0.y + v1.y) + (v2.y + v3.y);
  }
  for (; e < end; ++e) {
    int s0 = csr[e];
    float2 v0 = *(const float2*)(zp + (size_t)s0 * 64);
    ax += v0.x; ay += v0.y;
  }
  float inv = 1.0f / (float)max(end - start, 1);
  size_t o = (size_t)n * 64 + sl * 2;
  float vx = out[o] + ax * inv;
  float vy = out[o + 1] + ay * inv;
  float m = fmaxf(vx, vy);
#pragma unroll
  for (int off = 16; off > 0; off >>= 1) m = fmaxf(m, __shfl_xor(m, off, 64));
  float ex = expf(vx - m);
  float ey = expf(vy - m);
  float s = ex + ey;
#pragma unroll
  for (int off = 16; off > 0; off >>= 1) s += __shfl_xor(s, off, 64);
  float r = 1.0f / s;
  out[o] = ex * r;
  out[o + 1] = ey * r;
}

extern "C" void kernel_launch(void* const* d_in, const int* in_sizes, int n_in,
                              void* d_out, int out_size, void* d_ws, size_t ws_size,
                              hipStream_t stream) {
  const float* x   = (const float*)d_in[0];
  const int* src   = (const int*)d_in[1];
  const int* dst   = (const int*)d_in[2];
  const float* Ws0 = (const float*)d_in[3];
  const float* Wn0 = (const float*)d_in[4];
  const float* b0  = (const float*)d_in[5];
  const float* Ws1 = (const float*)d_in[6];
  const float* Wn1 = (const float*)d_in[7];
  const float* b1  = (const float*)d_in[8];
  const float* Ws2 = (const float*)d_in[9];
  const float* Wn2 = (const float*)d_in[10];
  const float* b2  = (const float*)d_in[11];
  float* out = (float*)d_out;

  // ws layout: cursor int[50048] | csr int[800000] | A=h1 25.6MB | B=h2 25.6MB | C 25.6MB
  char* ws = (char*)d_ws;
  int* cursor = (int*)ws;
  int* csr    = (int*)(ws + 200192);
  float* h1   = (float*)(ws + 3400192);
  float* h2   = (float*)(ws + 29000192);
  char* Creg  = ws + 54600192;
  unsigned* meanPk = (unsigned*)Creg;
  float* zbuf      = (float*)Creg;
  int* cnt         = (int*)Creg;
  int* bsum        = (int*)(Creg + N_NODES * sizeof(int));

  // split weights staged in d_out (12.8 MB; overwritten by layer-2 output later)
  unsigned short* W = (unsigned short*)d_out;
  unsigned short* wt0h = W;
  unsigned short* wt0l = W + 32768;
  unsigned short* wt1h = W + 65536;
  unsigned short* wt1l = W + 98304;
  unsigned short* wt2h = W + 131072;
  unsigned short* wt2l = W + 147456;
  float* b2ext = (float*)(W + 163840);

  // layer-2 weight copy target: A region (h1 is dead by then)
  unsigned short* wt2hc = (unsigned short*)h1;
  unsigned short* wt2lc = wt2hc + 16384;
  float* b2extc = (float*)(wt2hc + 32768);

  // CSR build (parallel 2-level scan)
  hipMemsetAsync(cnt, 0, N_NODES * sizeof(int), stream);
  hist_kernel<<<3125, 256, 0, stream>>>(dst, cnt);
  scan1_kernel<<<SCAN_B, 256, 0, stream>>>(cnt, cursor, bsum);
  scan2_kernel<<<1, 256, 0, stream>>>(bsum);
  scan3_kernel<<<SCAN_B, 256, 0, stream>>>(cursor, bsum);
  fill_kernel<<<3125, 256, 0, stream>>>(src, dst, cursor, csr);
  wsplit_kernel<<<321, 256, 0, stream>>>(Ws0, Wn0, Ws1, Wn1, Ws2, Wn2, b2,
                                         wt0h, wt0l, wt1h, wt1l, wt2h, wt2l, b2ext);

  // layer 0: x -> h1 (selu)
  gather_split<<<12500, 256, 0, stream>>>(x, cursor, csr, meanPk);
  gemm_direct<2, 2, 1, 0><<<782, 256, 0, stream>>>(x, meanPk, wt0h, wt0l, b0, h1, nullptr);

  // layer 1: h1 -> h2 (selu)
  gather_split<<<12500, 256, 0, stream>>>(h1, cursor, csr, meanPk);
  gemm_direct<2, 2, 1, 0><<<782, 256, 0, stream>>>(h1, meanPk, wt1h, wt1l, b1, h2, nullptr);

  // layer 2: u = h2@Ws2 + b2 -> out ; z = h2@Wn2 -> zbuf ; then mean(z) + u -> softmax
  hipMemcpyAsync(wt2hc, wt2h, 66048, hipMemcpyDeviceToDevice, stream);
  gemm_direct<2, 0, 0, 1><<<782, 256, 0, stream>>>(h2, nullptr, wt2hc, wt2lc, b2extc, out, zbuf);
  gather_sm<<<6250, 256, 0, stream>>>(zbuf, cursor, csr, out);
}

// Round 6
// 442.542 us; speedup vs baseline: 10.3933x; 1.0009x over previous
//
#include <hip/hip_runtime.h>
#include <hip/hip_bf16.h>

#define N_NODES 50000
#define N_EDGES 800000
#define D 128
#define SCAN_B 196  // ceil(N_NODES/256)

typedef __attribute__((ext_vector_type(8))) __bf16 bf16x8;
typedef __attribute__((ext_vector_type(4))) float f32x4;

union U8 {
  bf16x8 v;
  uint4 u;
};

// ---- fp32 -> bf16 split helpers (RNE; used in precompute/gather) ----
__device__ __forceinline__ unsigned short bf16_rne(float x) {
  unsigned u = __builtin_bit_cast(unsigned, x);
  unsigned r = u + 0x7fffu + ((u >> 16) & 1u);
  return (unsigned short)(r >> 16);
}
__device__ __forceinline__ float bf16_f(unsigned short b) {
  unsigned u = ((unsigned)b) << 16;
  return __builtin_bit_cast(float, u);
}
__device__ __forceinline__ void split2(float x, unsigned short& hi, unsigned short& lo) {
  hi = bf16_rne(x);
  lo = bf16_rne(x - bf16_f(hi));
}

__device__ __forceinline__ float selu_f(float x) {
  const float alpha = 1.6732632423543772f;
  const float scale = 1.0507009873554805f;
  return scale * (x > 0.0f ? x : alpha * expm1f(x));
}

// ================= CSR build =================
__global__ __launch_bounds__(256) void hist_kernel(const int* __restrict__ dst,
                                                   int* __restrict__ cnt) {
  int e = blockIdx.x * 256 + threadIdx.x;
  if (e < N_EDGES) atomicAdd(&cnt[dst[e]], 1);
}

__global__ __launch_bounds__(256) void scan1_kernel(const int* __restrict__ cnt,
                                                    int* __restrict__ cursor,
                                                    int* __restrict__ bsum) {
  __shared__ int s[256];
  const int t = threadIdx.x;
  const int i = blockIdx.x * 256 + t;
  int v = (i < N_NODES) ? cnt[i] : 0;
  s[t] = v;
  __syncthreads();
#pragma unroll
  for (int off = 1; off < 256; off <<= 1) {
    int u = (t >= off) ? s[t - off] : 0;
    __syncthreads();
    s[t] += u;
    __syncthreads();
  }
  if (i < N_NODES) cursor[i] = s[t] - v;
  if (t == 255) bsum[blockIdx.x] = s[255];
}

__global__ __launch_bounds__(256) void scan2_kernel(int* __restrict__ bsum) {
  __shared__ int s[256];
  const int t = threadIdx.x;
  int v = (t < SCAN_B) ? bsum[t] : 0;
  s[t] = v;
  __syncthreads();
#pragma unroll
  for (int off = 1; off < 256; off <<= 1) {
    int u = (t >= off) ? s[t - off] : 0;
    __syncthreads();
    s[t] += u;
    __syncthreads();
  }
  if (t < SCAN_B) bsum[t] = s[t] - v;
}

__global__ __launch_bounds__(256) void scan3_kernel(int* __restrict__ cursor,
                                                    const int* __restrict__ bsum) {
  const int i = blockIdx.x * 256 + threadIdx.x;
  if (i < N_NODES) cursor[i] += bsum[blockIdx.x];
}

__global__ __launch_bounds__(256) void fill_kernel(const int* __restrict__ src,
                                                   const int* __restrict__ dst,
                                                   int* __restrict__ cursor,
                                                   int* __restrict__ csr_src) {
  int e = blockIdx.x * 256 + threadIdx.x;
  if (e < N_EDGES) {
    int pos = atomicAdd(&cursor[dst[e]], 1);
    csr_src[pos] = src[e];
  }
}

// ================= weight split/transpose precompute =================
__global__ __launch_bounds__(256) void wsplit_kernel(
    const float* __restrict__ Ws0, const float* __restrict__ Wn0,
    const float* __restrict__ Ws1, const float* __restrict__ Wn1,
    const float* __restrict__ Ws2, const float* __restrict__ Wn2,
    const float* __restrict__ b2,
    unsigned short* __restrict__ wt0h, unsigned short* __restrict__ wt0l,
    unsigned short* __restrict__ wt1h, unsigned short* __restrict__ wt1l,
    unsigned short* __restrict__ wt2h, unsigned short* __restrict__ wt2l,
    float* __restrict__ b2ext) {
  int idx = blockIdx.x * 256 + threadIdx.x;
  if (idx < 32768) {
    int n = idx >> 8, k = idx & 255;
    float wv = (k < 128) ? Ws0[k * 128 + n] : Wn0[(k - 128) * 128 + n];
    unsigned short h, l; split2(wv, h, l);
    wt0h[idx] = h; wt0l[idx] = l;
  } else if (idx < 65536) {
    int j = idx - 32768;
    int n = j >> 8, k = j & 255;
    float wv = (k < 128) ? Ws1[k * 128 + n] : Wn1[(k - 128) * 128 + n];
    unsigned short h, l; split2(wv, h, l);
    wt1h[j] = h; wt1l[j] = l;
  } else if (idx < 81920) {
    int j = idx - 65536;
    int n = j >> 7, k = j & 127;
    float wv = (n < 64) ? Ws2[k * 64 + n] : Wn2[k * 64 + (n - 64)];
    unsigned short h, l; split2(wv, h, l);
    wt2h[j] = h; wt2l[j] = l;
  } else if (idx < 82048) {
    int c = idx - 81920;
    b2ext[c] = (c < 64) ? b2[c] : 0.0f;
  }
}

// ================= gather-mean -> packed bf16 hi/lo =================
__global__ __launch_bounds__(256) void gather_split(const float* __restrict__ h,
                                                    const int* __restrict__ cursor,
                                                    const int* __restrict__ csr,
                                                    unsigned* __restrict__ meanPk) {
  const int n = blockIdx.x * 4 + (threadIdx.x >> 6);
  const int lane = threadIdx.x & 63;
  const int end = cursor[n];
  const int start = (n == 0) ? 0 : cursor[n - 1];
  const float* hp = h + lane * 2;
  float ax = 0.f, ay = 0.f;
  int e = start;
  for (; e + 3 < end; e += 4) {
    int s0 = csr[e], s1 = csr[e + 1], s2 = csr[e + 2], s3 = csr[e + 3];
    float2 v0 = *(const float2*)(hp + (size_t)s0 * D);
    float2 v1 = *(const float2*)(hp + (size_t)s1 * D);
    float2 v2 = *(const float2*)(hp + (size_t)s2 * D);
    float2 v3 = *(const float2*)(hp + (size_t)s3 * D);
    ax += (v0.x + v1.x) + (v2.x + v3.x);
    ay += (v0.y + v1.y) + (v2.y + v3.y);
  }
  for (; e < end; ++e) {
    int s0 = csr[e];
    float2 v0 = *(const float2*)(hp + (size_t)s0 * D);
    ax += v0.x; ay += v0.y;
  }
  float inv = 1.0f / (float)max(end - start, 1);
  ax *= inv; ay *= inv;
  unsigned short hx, lx, hy, ly;
  split2(ax, hx, lx);
  split2(ay, hy, ly);
  uint2 pk;
  pk.x = (unsigned)hx | ((unsigned)lx << 16);
  pk.y = (unsigned)hy | ((unsigned)ly << 16);
  *(uint2*)(meanPk + (size_t)n * D + lane * 2) = pk;
}

// ================= bf16x3-split MFMA GEMM v2 =================
// Barrier-free, LDS-free. Wave = 16 rows x 64 cols (4 nf), col half from blockIdx.y.
// B loads batched into register arrays; accumulator split into 2 independent chains.
template <int QH, int QM, int ACT, int SPLIT>
__global__ __launch_bounds__(256, 4) void gemm_direct(const float* __restrict__ hsrc,
                                                      const unsigned* __restrict__ meanPk,
                                                      const unsigned short* __restrict__ wth,
                                                      const unsigned short* __restrict__ wtl,
                                                      const float* __restrict__ bias,
                                                      float* __restrict__ out0,
                                                      float* __restrict__ out1) {
  constexpr int NQ = QH + QM;
  constexpr int K = NQ * 64;
  const int tid = threadIdx.x;
  const int w = tid >> 6;
  const int l = tid & 63;
  const int lr = l & 15;
  const int lg = l >> 4;
  const int cb = blockIdx.y;  // column half (0: cols 0-63, 1: cols 64-127)
  const int row0 = blockIdx.x * 64;
  const int grow0 = row0 + w * 16 + lr;
  const int arow = min(grow0, N_NODES - 1);

  const float* ap = hsrc + (size_t)arow * D;
  const unsigned* mp = meanPk + (size_t)arow * D;
  const unsigned short* bhp = wth + (size_t)(cb * 64 + lr) * K;
  const unsigned short* blp = wtl + (size_t)(cb * 64 + lr) * K;

  f32x4 accA[4], accB[4];
#pragma unroll
  for (int i = 0; i < 4; ++i) {
    accA[i] = (f32x4){0.f, 0.f, 0.f, 0.f};
    accB[i] = (f32x4){0.f, 0.f, 0.f, 0.f};
  }

#pragma unroll
  for (int q = 0; q < NQ; ++q) {
#pragma unroll
    for (int kt = 0; kt < 2; ++kt) {
      const int k0 = q * 64 + kt * 32 + lg * 8;
      // ---- batched B loads (8 independent 16B loads issue back-to-back) ----
      U8 bh[4], bl[4];
#pragma unroll
      for (int nf = 0; nf < 4; ++nf) {
        bh[nf].u = *(const uint4*)(bhp + (size_t)nf * 16 * K + k0);
        bl[nf].u = *(const uint4*)(blp + (size_t)nf * 16 * K + k0);
      }
      // ---- A fragment (split in registers) ----
      U8 ah, al;
      if (q < QH) {
        float4 v0 = *(const float4*)(ap + k0);
        float4 v1 = *(const float4*)(ap + k0 + 4);
        unsigned u0 = __builtin_bit_cast(unsigned, v0.x);
        unsigned u1 = __builtin_bit_cast(unsigned, v0.y);
        unsigned u2 = __builtin_bit_cast(unsigned, v0.z);
        unsigned u3 = __builtin_bit_cast(unsigned, v0.w);
        unsigned u4 = __builtin_bit_cast(unsigned, v1.x);
        unsigned u5 = __builtin_bit_cast(unsigned, v1.y);
        unsigned u6 = __builtin_bit_cast(unsigned, v1.z);
        unsigned u7 = __builtin_bit_cast(unsigned, v1.w);
        ah.u.x = (u0 >> 16) | (u1 & 0xffff0000u);
        ah.u.y = (u2 >> 16) | (u3 & 0xffff0000u);
        ah.u.z = (u4 >> 16) | (u5 & 0xffff0000u);
        ah.u.w = (u6 >> 16) | (u7 & 0xffff0000u);
        unsigned r0 = __builtin_bit_cast(unsigned, v0.x - __builtin_bit_cast(float, u0 & 0xffff0000u));
        unsigned r1 = __builtin_bit_cast(unsigned, v0.y - __builtin_bit_cast(float, u1 & 0xffff0000u));
        unsigned r2 = __builtin_bit_cast(unsigned, v0.z - __builtin_bit_cast(float, u2 & 0xffff0000u));
        unsigned r3 = __builtin_bit_cast(unsigned, v0.w - __builtin_bit_cast(float, u3 & 0xffff0000u));
        unsigned r4 = __builtin_bit_cast(unsigned, v1.x - __builtin_bit_cast(float, u4 & 0xffff0000u));
        unsigned r5 = __builtin_bit_cast(unsigned, v1.y - __builtin_bit_cast(float, u5 & 0xffff0000u));
        unsigned r6 = __builtin_bit_cast(unsigned, v1.z - __builtin_bit_cast(float, u6 & 0xffff0000u));
        unsigned r7 = __builtin_bit_cast(unsigned, v1.w - __builtin_bit_cast(float, u7 & 0xffff0000u));
        al.u.x = (r0 >> 16) | (r1 & 0xffff0000u);
        al.u.y = (r2 >> 16) | (r3 & 0xffff0000u);
        al.u.z = (r4 >> 16) | (r5 & 0xffff0000u);
        al.u.w = (r6 >> 16) | (r7 & 0xffff0000u);
      } else {
        const int c0 = (q - QH) * 64 + kt * 32 + lg * 8;
        uint4 p0 = *(const uint4*)(mp + c0);
        uint4 p1 = *(const uint4*)(mp + c0 + 4);
        ah.u.x = (p0.x & 0xffffu) | (p0.y << 16);
        ah.u.y = (p0.z & 0xffffu) | (p0.w << 16);
        ah.u.z = (p1.x & 0xffffu) | (p1.y << 16);
        ah.u.w = (p1.z & 0xffffu) | (p1.w << 16);
        al.u.x = (p0.x >> 16) | (p0.y & 0xffff0000u);
        al.u.y = (p0.z >> 16) | (p0.w & 0xffff0000u);
        al.u.z = (p1.x >> 16) | (p1.y & 0xffff0000u);
        al.u.w = (p1.z >> 16) | (p1.w & 0xffff0000u);
      }
      // ---- MFMA: 8 independent chains (accA: 1 op, accB: 2 deps) ----
#pragma unroll
      for (int nf = 0; nf < 4; ++nf) {
        accA[nf] = __builtin_amdgcn_mfma_f32_16x16x32_bf16(ah.v, bh[nf].v, accA[nf], 0, 0, 0);
        accB[nf] = __builtin_amdgcn_mfma_f32_16x16x32_bf16(al.v, bh[nf].v, accB[nf], 0, 0, 0);
        accB[nf] = __builtin_amdgcn_mfma_f32_16x16x32_bf16(ah.v, bl[nf].v, accB[nf], 0, 0, 0);
      }
    }
  }
  // epilogue: C col = cb*64 + nf*16 + lr, row = lg*4 + i (within wave's 16 rows)
#pragma unroll
  for (int nf = 0; nf < 4; ++nf) {
    const int col = cb * 64 + nf * 16 + lr;
    const float bv = bias[col];
#pragma unroll
    for (int i = 0; i < 4; ++i) {
      const int grow = row0 + w * 16 + lg * 4 + i;
      if (grow < N_NODES) {
        float v = accA[nf][i] + accB[nf][i] + bv;
        if (ACT) v = selu_f(v);
        if (SPLIT) {
          if (col < 64) out0[(size_t)grow * 64 + col] = v;
          else out1[(size_t)grow * 64 + (col - 64)] = v;
        } else {
          out0[(size_t)grow * D + col] = v;
        }
      }
    }
  }
}

// ================= fused gather(z) + add(u) + softmax =================
__global__ __launch_bounds__(256) void gather_sm(const float* __restrict__ zbuf,
                                                 const int* __restrict__ cursor,
                                                 const int* __restrict__ csr,
                                                 float* __restrict__ out) {
  const int n = blockIdx.x * 8 + (threadIdx.x >> 5);
  const int sl = threadIdx.x & 31;
  const int end = cursor[n];
  const int start = (n == 0) ? 0 : cursor[n - 1];
  const float* zp = zbuf + sl * 2;
  float ax = 0.f, ay = 0.f;
  int e = start;
  for (; e + 3 < end; e += 4) {
    int s0 = csr[e], s1 = csr[e + 1], s2 = csr[e + 2], s3 = csr[e + 3];
    float2 v0 = *(const float2*)(zp + (size_t)s0 * 64);
    float2 v1 = *(const float2*)(zp + (size_t)s1 * 64);
    float2 v2 = *(const float2*)(zp + (size_t)s2 * 64);
    float2 v3 = *(const float2*)(zp + (size_t)s3 * 64);
    ax += (v0.x + v1.x) + (v2.x + v3.x);
    ay += (v0.y + v1.y) + (v2.y + v3.y);
  }
  for (; e < end; ++e) {
    int s0 = csr[e];
    float2 v0 = *(const float2*)(zp + (size_t)s0 * 64);
    ax += v0.x; ay += v0.y;
  }
  float inv = 1.0f / (float)max(end - start, 1);
  size_t o = (size_t)n * 64 + sl * 2;
  float vx = out[o] + ax * inv;
  float vy = out[o + 1] + ay * inv;
  float m = fmaxf(vx, vy);
#pragma unroll
  for (int off = 16; off > 0; off >>= 1) m = fmaxf(m, __shfl_xor(m, off, 64));
  float ex = expf(vx - m);
  float ey = expf(vy - m);
  float s = ex + ey;
#pragma unroll
  for (int off = 16; off > 0; off >>= 1) s += __shfl_xor(s, off, 64);
  float r = 1.0f / s;
  out[o] = ex * r;
  out[o + 1] = ey * r;
}

extern "C" void kernel_launch(void* const* d_in, const int* in_sizes, int n_in,
                              void* d_out, int out_size, void* d_ws, size_t ws_size,
                              hipStream_t stream) {
  const float* x   = (const float*)d_in[0];
  const int* src   = (const int*)d_in[1];
  const int* dst   = (const int*)d_in[2];
  const float* Ws0 = (const float*)d_in[3];
  const float* Wn0 = (const float*)d_in[4];
  const float* b0  = (const float*)d_in[5];
  const float* Ws1 = (const float*)d_in[6];
  const float* Wn1 = (const float*)d_in[7];
  const float* b1  = (const float*)d_in[8];
  const float* Ws2 = (const float*)d_in[9];
  const float* Wn2 = (const float*)d_in[10];
  const float* b2  = (const float*)d_in[11];
  float* out = (float*)d_out;

  // ws layout: cursor int[50048] | csr int[800000] | A=h1 25.6MB | B=h2 25.6MB | C 25.6MB
  char* ws = (char*)d_ws;
  int* cursor = (int*)ws;
  int* csr    = (int*)(ws + 200192);
  float* h1   = (float*)(ws + 3400192);
  float* h2   = (float*)(ws + 29000192);
  char* Creg  = ws + 54600192;
  unsigned* meanPk = (unsigned*)Creg;
  float* zbuf      = (float*)Creg;
  int* cnt         = (int*)Creg;
  int* bsum        = (int*)(Creg + N_NODES * sizeof(int));

  // split weights staged in d_out (12.8 MB; overwritten by layer-2 output later)
  unsigned short* W = (unsigned short*)d_out;
  unsigned short* wt0h = W;
  unsigned short* wt0l = W + 32768;
  unsigned short* wt1h = W + 65536;
  unsigned short* wt1l = W + 98304;
  unsigned short* wt2h = W + 131072;
  unsigned short* wt2l = W + 147456;
  float* b2ext = (float*)(W + 163840);

  // layer-2 weight copy target: A region (h1 is dead by then)
  unsigned short* wt2hc = (unsigned short*)h1;
  unsigned short* wt2lc = wt2hc + 16384;
  float* b2extc = (float*)(wt2hc + 32768);

  // CSR build (parallel 2-level scan)
  hipMemsetAsync(cnt, 0, N_NODES * sizeof(int), stream);
  hist_kernel<<<3125, 256, 0, stream>>>(dst, cnt);
  scan1_kernel<<<SCAN_B, 256, 0, stream>>>(cnt, cursor, bsum);
  scan2_kernel<<<1, 256, 0, stream>>>(bsum);
  scan3_kernel<<<SCAN_B, 256, 0, stream>>>(cursor, bsum);
  fill_kernel<<<3125, 256, 0, stream>>>(src, dst, cursor, csr);
  wsplit_kernel<<<321, 256, 0, stream>>>(Ws0, Wn0, Ws1, Wn1, Ws2, Wn2, b2,
                                         wt0h, wt0l, wt1h, wt1l, wt2h, wt2l, b2ext);

  // layer 0: x -> h1 (selu)
  gather_split<<<12500, 256, 0, stream>>>(x, cursor, csr, meanPk);
  gemm_direct<2, 2, 1, 0><<<dim3(782, 2), 256, 0, stream>>>(x, meanPk, wt0h, wt0l, b0, h1, nullptr);

  // layer 1: h1 -> h2 (selu)
  gather_split<<<12500, 256, 0, stream>>>(h1, cursor, csr, meanPk);
  gemm_direct<2, 2, 1, 0><<<dim3(782, 2), 256, 0, stream>>>(h1, meanPk, wt1h, wt1l, b1, h2, nullptr);

  // layer 2: u = h2@Ws2 + b2 -> out ; z = h2@Wn2 -> zbuf ; then mean(z) + u -> softmax
  hipMemcpyAsync(wt2hc, wt2h, 66048, hipMemcpyDeviceToDevice, stream);
  gemm_direct<2, 0, 0, 1><<<dim3(782, 2), 256, 0, stream>>>(h2, nullptr, wt2hc, wt2lc, b2extc, out, zbuf);
  gather_sm<<<6250, 256, 0, stream>>>(zbuf, cursor, csr, out);
}